// Round 2
// baseline (600.466 us; speedup 1.0000x reference)
//
#include <hip/hip_runtime.h>
#include <hip/hip_bf16.h>

// MLA forward, MI355X/gfx950.
// B=4, S=2048, D_MODEL=1024, H=16, D_H=64, D_HR=32, D_LATENT=256, d_qk=96.

typedef __attribute__((ext_vector_type(8))) __bf16 bf16x8;
typedef __attribute__((ext_vector_type(4))) float f32x4;
typedef __attribute__((ext_vector_type(4))) unsigned short us4;

#define DEV static __device__ __forceinline__

DEV unsigned short f2b(float f) {
  union { __hip_bfloat16 h; unsigned short u; } v;
  v.h = __float2bfloat16(f);
  return v.u;
}
DEV float b2f(unsigned short u) {
  union { unsigned short u; __hip_bfloat16 h; } v;
  v.u = u;
  return __bfloat162float(v.h);
}
DEV f32x4 mfma16(bf16x8 a, bf16x8 b, f32x4 c) {
  return __builtin_amdgcn_mfma_f32_16x16x32_bf16(a, b, c, 0, 0, 0);
}
DEV void load_lds16(const void* g, void* lds) {
  __builtin_amdgcn_global_load_lds((__attribute__((address_space(1))) void*)g,
                                   (__attribute__((address_space(3))) void*)lds,
                                   16, 0, 0);
}

// ---------------- convert x (fp32 -> bf16) ----------------
__global__ __launch_bounds__(256) void convert_x(const float* __restrict__ x,
                                                 unsigned short* __restrict__ xb) {
  long i = (long)(blockIdx.x * 256 + threadIdx.x) * 4;
  float4 v = *(const float4*)(x + i);
  us4 o = { f2b(v.x), f2b(v.y), f2b(v.z), f2b(v.w) };
  *(us4*)(xb + i) = o;
}

// ---------------- weight transpose: W (K x N) fp32 -> WT (N x K) bf16 ----------------
__global__ __launch_bounds__(256) void transpose_w(const float* __restrict__ W,
                                                   unsigned short* __restrict__ WT,
                                                   int K, int N) {
  __shared__ float tile[32][33];
  int tx = threadIdx.x & 31, ty = threadIdx.x >> 5;
  int n0 = blockIdx.x * 32, k0 = blockIdx.y * 32;
#pragma unroll
  for (int i = 0; i < 32; i += 8) {
    int k = k0 + ty + i, n = n0 + tx;
    tile[ty + i][tx] = (k < K && n < N) ? W[(long)k * N + n] : 0.f;
  }
  __syncthreads();
#pragma unroll
  for (int i = 0; i < 32; i += 8) {
    int n = n0 + ty + i, k = k0 + tx;
    if (n < N && k < K) WT[(long)n * K + k] = f2b(tile[tx][ty + i]);
  }
}

// ---------------- V transpose: C3 (B*S x 2048, V at cols 1024+h*64+d) -> Vt[bh*64+d][s] ----------------
__global__ __launch_bounds__(256) void transpose_v(const unsigned short* __restrict__ C3,
                                                   unsigned short* __restrict__ Vt) {
  __shared__ unsigned short tile[32][33];
  int bh = blockIdx.z, b = bh >> 4, h = bh & 15;
  int d0 = blockIdx.x * 32, s0 = blockIdx.y * 32;
  int tx = threadIdx.x & 31, ty = threadIdx.x >> 5;
#pragma unroll
  for (int i = 0; i < 32; i += 8) {
    int s = s0 + ty + i, d = d0 + tx;
    tile[ty + i][tx] = C3[(long)(b * 2048 + s) * 2048 + 1024 + h * 64 + d];
  }
  __syncthreads();
#pragma unroll
  for (int i = 0; i < 32; i += 8) {
    int d = d0 + ty + i, s = s0 + tx;
    Vt[(long)(bh * 64 + d) * 2048 + s] = tile[tx][ty + i];  // FIXED: was s0+2*tx garbage
  }
}

// ---------------- RoPE on Qr, in-place in C2 (cols 1024 + h*32 + 2i, 2i+1) ----------------
__global__ __launch_bounds__(256) void rope_q(unsigned short* __restrict__ C2) {
  int idx = blockIdx.x * 256 + threadIdx.x;   // 2^21 threads exact
  int i = idx & 15, h = (idx >> 4) & 15, s = (idx >> 8) & 2047, b = idx >> 19;
  long base = (long)(b * 2048 + s) * 1536 + 1024 + h * 32 + 2 * i;
  float x1 = b2f(C2[base]), x2 = b2f(C2[base + 1]);
  float inv = exp2f(-(float)i * 0.8304820237686285f);  // 10000^(-i/16)
  float ang = (float)s * inv;
  float c = cosf(ang), sn = sinf(ang);
  C2[base]     = f2b(x1 * c - x2 * sn);
  C2[base + 1] = f2b(x1 * sn + x2 * c);
}

// ---------------- RoPE on Kr: C1 cols 512+2i -> Krr (B*S x 32) ----------------
__global__ __launch_bounds__(256) void rope_k(const unsigned short* __restrict__ C1,
                                              unsigned short* __restrict__ Krr) {
  int idx = blockIdx.x * 256 + threadIdx.x;   // 2^17 threads exact
  int i = idx & 15, s = (idx >> 4) & 2047, b = idx >> 15;
  long src = (long)(b * 2048 + s) * 544 + 512 + 2 * i;
  float x1 = b2f(C1[src]), x2 = b2f(C1[src + 1]);
  float inv = exp2f(-(float)i * 0.8304820237686285f);
  float ang = (float)s * inv;
  float c = cosf(ang), sn = sinf(ang);
  long dst = (long)(b * 2048 + s) * 32 + 2 * i;
  Krr[dst]     = f2b(x1 * c - x2 * sn);
  Krr[dst + 1] = f2b(x1 * sn + x2 * c);
}

// ---------------- GEMM: C(M x N) = A(M x K, lda) @ Bt(N x K, ldb)^T ----------------
// m97-style: 128x128 tile, BK=32, 4 waves (2x2), 16x16x32 bf16 MFMA,
// global_load_lds width-16 staging. M must be a multiple of 128 (it is: 8192).
template <bool OUT_BF16>
__global__ __launch_bounds__(256) void gemm_bt(const unsigned short* __restrict__ A, int lda,
                                               const unsigned short* __restrict__ Bt, int ldb,
                                               void* __restrict__ Cv, int ldc, int N, int K) {
  __shared__ __align__(16) unsigned short As[128 * 32];
  __shared__ __align__(16) unsigned short Bs[128 * 32];
  const int t = threadIdx.x;
  const int w = t >> 6, lane = t & 63, ln = lane & 15, quad = lane >> 4;
  const int wr = w >> 1, wc = w & 1;
  const int bm0 = blockIdx.x * 128, bn0 = blockIdx.y * 128;
  const int srow = t >> 2;          // 0..63
  const int scol = (t & 3) * 8;     // 0,8,16,24
  f32x4 zero = {0.f, 0.f, 0.f, 0.f};
  f32x4 acc[4][4];
#pragma unroll
  for (int i = 0; i < 4; ++i)
#pragma unroll
    for (int j = 0; j < 4; ++j) acc[i][j] = zero;

  for (int k0 = 0; k0 < K; k0 += 32) {
#pragma unroll
    for (int r = 0; r < 2; ++r) {
      int arow = bm0 + r * 64 + srow;
      load_lds16(A + (long)arow * lda + k0 + scol, (char*)As + r * 4096 + w * 1024);
      int brow = bn0 + r * 64 + srow;
      if (brow > N - 1) brow = N - 1;  // clamp (garbage cols guarded at write)
      load_lds16(Bt + (long)brow * ldb + k0 + scol, (char*)Bs + r * 4096 + w * 1024);
    }
    __syncthreads();  // drains vmcnt(0) before barrier -> LDS data visible
    bf16x8 af[4], bf[4];
#pragma unroll
    for (int i = 0; i < 4; ++i)
      af[i] = *(const bf16x8*)(As + (wr * 64 + i * 16 + ln) * 32 + quad * 8);
#pragma unroll
    for (int j = 0; j < 4; ++j)
      bf[j] = *(const bf16x8*)(Bs + (wc * 64 + j * 16 + ln) * 32 + quad * 8);
#pragma unroll
    for (int i = 0; i < 4; ++i)
#pragma unroll
      for (int j = 0; j < 4; ++j) acc[i][j] = mfma16(af[i], bf[j], acc[i][j]);
    __syncthreads();
  }
  // epilogue: D layout col=lane&15, row=quad*4+reg
#pragma unroll
  for (int i = 0; i < 4; ++i)
#pragma unroll
    for (int j = 0; j < 4; ++j)
#pragma unroll
      for (int r = 0; r < 4; ++r) {
        int row = bm0 + wr * 64 + i * 16 + quad * 4 + r;
        int col = bn0 + wc * 64 + j * 16 + ln;
        if (col < N) {
          if (OUT_BF16)
            ((unsigned short*)Cv)[(long)row * ldc + col] = f2b(acc[i][j][r]);
          else
            ((float*)Cv)[(long)row * ldc + col] = acc[i][j][r];
        }
      }
}

// ---------------- Flash attention ----------------
// grid (S/128, B*H), 256 thr. Wave w owns 32 Q rows (2 m-tiles of 16).
// Q read from C2 (Qc cols h*64.., roped Qr cols 1024+h*32..),
// K from C3 (Kc) + Krr (roped, head-shared), V from Vt (d-major).
__global__ __launch_bounds__(256) void flash_attn(const unsigned short* __restrict__ C2,
                                                  const unsigned short* __restrict__ C3,
                                                  const unsigned short* __restrict__ Krr,
                                                  const unsigned short* __restrict__ Vt,
                                                  unsigned short* __restrict__ Oa) {
  __shared__ __align__(16) unsigned short Plds[4][2][16 * 32];  // per-wave, per-mi
  const int tid = threadIdx.x;
  const int w = tid >> 6, lane = tid & 63, ln = lane & 15, quad = lane >> 4;
  const int bh = blockIdx.y, b = bh >> 4, h = bh & 15;
  const int qb = blockIdx.x * 128 + w * 32;
  const float scale = 0.10206207261596577f;  // 1/sqrt(96)

  bf16x8 qf[2][3];
#pragma unroll
  for (int mi = 0; mi < 2; ++mi) {
    const unsigned short* qp = C2 + (long)(b * 2048 + qb + mi * 16 + ln) * 1536;
    qf[mi][0] = *(const bf16x8*)(qp + h * 64 + quad * 8);
    qf[mi][1] = *(const bf16x8*)(qp + h * 64 + 32 + quad * 8);
    qf[mi][2] = *(const bf16x8*)(qp + 1024 + h * 32 + quad * 8);
  }
  f32x4 zero = {0.f, 0.f, 0.f, 0.f};
  f32x4 o[2][4];
  float m_run[2][4], l_run[2][4];
#pragma unroll
  for (int mi = 0; mi < 2; ++mi) {
#pragma unroll
    for (int nb = 0; nb < 4; ++nb) o[mi][nb] = zero;
#pragma unroll
    for (int r = 0; r < 4; ++r) { m_run[mi][r] = -1e30f; l_run[mi][r] = 0.f; }
  }

  const int ktmax = qb >> 5;
  for (int kt = 0; kt <= ktmax; ++kt) {
    const int c0 = kt * 32;
    bf16x8 kf[2][3];
#pragma unroll
    for (int ni = 0; ni < 2; ++ni) {
      long krow = (long)(b * 2048 + c0 + ni * 16 + ln);
      const unsigned short* kp = C3 + krow * 2048;
      kf[ni][0] = *(const bf16x8*)(kp + h * 64 + quad * 8);
      kf[ni][1] = *(const bf16x8*)(kp + h * 64 + 32 + quad * 8);
      kf[ni][2] = *(const bf16x8*)(Krr + krow * 32 + quad * 8);
    }
    bf16x8 vf[4];
#pragma unroll
    for (int nb = 0; nb < 4; ++nb)
      vf[nb] = *(const bf16x8*)(Vt + (long)(bh * 64 + nb * 16 + ln) * 2048 + c0 + quad * 8);

#pragma unroll
    for (int mi = 0; mi < 2; ++mi) {
      f32x4 s0 = zero, s1 = zero;
#pragma unroll
      for (int kb = 0; kb < 3; ++kb) {
        s0 = mfma16(qf[mi][kb], kf[0][kb], s0);
        s1 = mfma16(qf[mi][kb], kf[1][kb], s1);
      }
      // clip(+-80) BEFORE scale; mask AFTER clip (matches reference order)
      float z0[4], z1[4], rm[4];
#pragma unroll
      for (int r = 0; r < 4; ++r) {
        int qrow = qb + mi * 16 + quad * 4 + r;
        float a0 = fminf(fmaxf(s0[r], -80.f), 80.f) * scale;
        float a1 = fminf(fmaxf(s1[r], -80.f), 80.f) * scale;
        z0[r] = (c0 + ln <= qrow) ? a0 : -1e30f;
        z1[r] = (c0 + 16 + ln <= qrow) ? a1 : -1e30f;
        rm[r] = fmaxf(z0[r], z1[r]);
      }
#pragma unroll
      for (int d = 1; d < 16; d <<= 1)
#pragma unroll
        for (int r = 0; r < 4; ++r) rm[r] = fmaxf(rm[r], __shfl_xor(rm[r], d, 64));
      float p0[4], p1[4], rs[4];
#pragma unroll
      for (int r = 0; r < 4; ++r) {
        float mn = fmaxf(m_run[mi][r], rm[r]);
        float al = __expf(m_run[mi][r] - mn);
        m_run[mi][r] = mn;
        p0[r] = __expf(z0[r] - mn);
        p1[r] = __expf(z1[r] - mn);
        rs[r] = p0[r] + p1[r];
        l_run[mi][r] *= al;
#pragma unroll
        for (int nb = 0; nb < 4; ++nb) o[mi][nb][r] *= al;
      }
#pragma unroll
      for (int d = 1; d < 16; d <<= 1)
#pragma unroll
        for (int r = 0; r < 4; ++r) rs[r] += __shfl_xor(rs[r], d, 64);
#pragma unroll
      for (int r = 0; r < 4; ++r) l_run[mi][r] += rs[r];
      // P: C-layout -> LDS -> A-layout (m120-verified transform)
      unsigned short* pl = &Plds[w][mi][0];
#pragma unroll
      for (int r = 0; r < 4; ++r) {
        pl[(quad * 4 + r) * 32 + ln] = f2b(p0[r]);
        pl[(quad * 4 + r) * 32 + 16 + ln] = f2b(p1[r]);
      }
      __threadfence_block();  // per-wave lgkmcnt drain; NO __syncthreads (divergent kt loop)
      bf16x8 pf = *(const bf16x8*)(pl + ln * 32 + quad * 8);
#pragma unroll
      for (int nb = 0; nb < 4; ++nb) o[mi][nb] = mfma16(pf, vf[nb], o[mi][nb]);
    }
  }
  // epilogue: Oa layout (B,S,H*64) bf16
#pragma unroll
  for (int mi = 0; mi < 2; ++mi)
#pragma unroll
    for (int nb = 0; nb < 4; ++nb)
#pragma unroll
      for (int r = 0; r < 4; ++r) {
        long row = (long)(b * 2048 + qb + mi * 16 + quad * 4 + r);
        Oa[row * 1024 + h * 64 + nb * 16 + ln] = f2b(o[mi][nb][r] / l_run[mi][r]);
      }
}

// ---------------- launcher ----------------
extern "C" void kernel_launch(void* const* d_in, const int* in_sizes, int n_in,
                              void* d_out, int out_size, void* d_ws, size_t ws_size,
                              hipStream_t stream) {
  (void)in_sizes; (void)n_in; (void)out_size; (void)ws_size;
  const float* x     = (const float*)d_in[0];
  const float* W_DQ  = (const float*)d_in[1];
  const float* W_UQ  = (const float*)d_in[2];
  const float* W_QR  = (const float*)d_in[3];
  const float* W_DKV = (const float*)d_in[4];
  const float* W_UK  = (const float*)d_in[5];
  const float* W_UV  = (const float*)d_in[6];
  const float* W_KR  = (const float*)d_in[7];
  const float* W_O   = (const float*)d_in[8];

  char* p = (char*)d_ws;
  unsigned short* xb  = (unsigned short*)p; p += (size_t)8192 * 1024 * 2;
  unsigned short* WT1 = (unsigned short*)p; p += (size_t)544 * 1024 * 2;   // [W_DQ^T; W_DKV^T; W_KR^T]
  unsigned short* WT2 = (unsigned short*)p; p += (size_t)1536 * 256 * 2;   // [W_UQ^T; W_QR^T]
  unsigned short* WT3 = (unsigned short*)p; p += (size_t)2048 * 256 * 2;   // [W_UK^T; W_UV^T]
  unsigned short* WT4 = (unsigned short*)p; p += (size_t)1024 * 1024 * 2;  // W_O^T
  unsigned short* C1  = (unsigned short*)p; p += (size_t)8192 * 544 * 2;   // [c_q | c_kv | kr_raw]
  unsigned short* C2  = (unsigned short*)p; p += (size_t)8192 * 1536 * 2;  // [Qc | Qr(roped in-place)]
  unsigned short* C3  = (unsigned short*)p; p += (size_t)8192 * 2048 * 2;  // [Kc | V]
  unsigned short* Krr = (unsigned short*)p; p += (size_t)8192 * 32 * 2;    // roped Kr
  unsigned short* Vt  = (unsigned short*)p; p += (size_t)64 * 64 * 2048 * 2;
  unsigned short* Oa  = (unsigned short*)p; p += (size_t)8192 * 1024 * 2;  // attn out (B,S,1024)

  convert_x<<<8192, 256, 0, stream>>>(x, xb);
  transpose_w<<<dim3(8, 32),  256, 0, stream>>>(W_DQ,  WT1,              1024, 256);
  transpose_w<<<dim3(8, 32),  256, 0, stream>>>(W_DKV, WT1 + 256 * 1024, 1024, 256);
  transpose_w<<<dim3(1, 32),  256, 0, stream>>>(W_KR,  WT1 + 512 * 1024, 1024, 32);
  transpose_w<<<dim3(32, 8),  256, 0, stream>>>(W_UQ,  WT2,              256, 1024);
  transpose_w<<<dim3(16, 8),  256, 0, stream>>>(W_QR,  WT2 + 1024 * 256, 256, 512);
  transpose_w<<<dim3(32, 8),  256, 0, stream>>>(W_UK,  WT3,              256, 1024);
  transpose_w<<<dim3(32, 8),  256, 0, stream>>>(W_UV,  WT3 + 1024 * 256, 256, 1024);
  transpose_w<<<dim3(32, 32), 256, 0, stream>>>(W_O,   WT4,              1024, 1024);

  gemm_bt<true><<<dim3(64, 5),  256, 0, stream>>>(xb, 1024, WT1, 1024, C1, 544, 544, 1024);
  rope_k<<<512, 256, 0, stream>>>(C1, Krr);
  gemm_bt<true><<<dim3(64, 12), 256, 0, stream>>>(C1, 544, WT2, 256, C2, 1536, 1536, 256);
  gemm_bt<true><<<dim3(64, 16), 256, 0, stream>>>(C1 + 256, 544, WT3, 256, C3, 2048, 2048, 256);
  rope_q<<<8192, 256, 0, stream>>>(C2);
  transpose_v<<<dim3(2, 64, 64), 256, 0, stream>>>(C3, Vt);
  flash_attn<<<dim3(16, 64), 256, 0, stream>>>(C2, C3, Krr, Vt, Oa);
  gemm_bt<false><<<dim3(64, 8), 256, 0, stream>>>(Oa, 1024, WT4, 1024, d_out, 1024, 1024, 1024);
}

// Round 3
// 383.163 us; speedup vs baseline: 1.5671x; 1.5671x over previous
//
#include <hip/hip_runtime.h>
#include <hip/hip_bf16.h>

// MLA forward, MI355X/gfx950.
// B=4, S=2048, D_MODEL=1024, H=16, D_H=64, D_HR=32, D_LATENT=256, d_qk=96.

typedef __attribute__((ext_vector_type(8))) __bf16 bf16x8;
typedef __attribute__((ext_vector_type(4))) float f32x4;
typedef __attribute__((ext_vector_type(4))) unsigned short us4;

#define DEV static __device__ __forceinline__

DEV unsigned short f2b(float f) {
  union { __hip_bfloat16 h; unsigned short u; } v;
  v.h = __float2bfloat16(f);
  return v.u;
}
DEV float b2f(unsigned short u) {
  union { unsigned short u; __hip_bfloat16 h; } v;
  v.u = u;
  return __bfloat162float(v.h);
}
DEV f32x4 mfma16(bf16x8 a, bf16x8 b, f32x4 c) {
  return __builtin_amdgcn_mfma_f32_16x16x32_bf16(a, b, c, 0, 0, 0);
}
DEV void load_lds16(const void* g, void* lds) {
  __builtin_amdgcn_global_load_lds((__attribute__((address_space(1))) void*)g,
                                   (__attribute__((address_space(3))) void*)lds,
                                   16, 0, 0);
}
DEV bf16x8 ones8() {
  union { unsigned short u[8]; bf16x8 v; } c;
#pragma unroll
  for (int i = 0; i < 8; ++i) c.u[i] = 0x3F80;  // bf16 1.0
  return c.v;
}

// ---------------- convert x (fp32 -> bf16) ----------------
__global__ __launch_bounds__(256) void convert_x(const float* __restrict__ x,
                                                 unsigned short* __restrict__ xb) {
  long i = (long)(blockIdx.x * 256 + threadIdx.x) * 4;
  float4 v = *(const float4*)(x + i);
  us4 o = { f2b(v.x), f2b(v.y), f2b(v.z), f2b(v.w) };
  *(us4*)(xb + i) = o;
}

// ---------------- weight transpose: W (K x N) fp32 -> WT (N x K) bf16 ----------------
__global__ __launch_bounds__(256) void transpose_w(const float* __restrict__ W,
                                                   unsigned short* __restrict__ WT,
                                                   int K, int N) {
  __shared__ float tile[32][33];
  int tx = threadIdx.x & 31, ty = threadIdx.x >> 5;
  int n0 = blockIdx.x * 32, k0 = blockIdx.y * 32;
#pragma unroll
  for (int i = 0; i < 32; i += 8) {
    int k = k0 + ty + i, n = n0 + tx;
    tile[ty + i][tx] = (k < K && n < N) ? W[(long)k * N + n] : 0.f;
  }
  __syncthreads();
#pragma unroll
  for (int i = 0; i < 32; i += 8) {
    int n = n0 + ty + i, k = k0 + tx;
    if (n < N && k < K) WT[(long)n * K + k] = f2b(tile[tx][ty + i]);
  }
}

// ---------------- V transpose: C3 (B*S x 2048, V at cols 1024+h*64+d) -> Vt[bh*64+d][s] ----------------
__global__ __launch_bounds__(256) void transpose_v(const unsigned short* __restrict__ C3,
                                                   unsigned short* __restrict__ Vt) {
  __shared__ unsigned short tile[32][33];
  int bh = blockIdx.z, b = bh >> 4, h = bh & 15;
  int d0 = blockIdx.x * 32, s0 = blockIdx.y * 32;
  int tx = threadIdx.x & 31, ty = threadIdx.x >> 5;
#pragma unroll
  for (int i = 0; i < 32; i += 8) {
    int s = s0 + ty + i, d = d0 + tx;
    tile[ty + i][tx] = C3[(long)(b * 2048 + s) * 2048 + 1024 + h * 64 + d];
  }
  __syncthreads();
#pragma unroll
  for (int i = 0; i < 32; i += 8) {
    int d = d0 + ty + i, s = s0 + tx;
    Vt[(long)(bh * 64 + d) * 2048 + s] = tile[tx][ty + i];
  }
}

// ---------------- RoPE on Qr, in-place in C2 (cols 1024 + h*32 + 2i, 2i+1) ----------------
__global__ __launch_bounds__(256) void rope_q(unsigned short* __restrict__ C2) {
  int idx = blockIdx.x * 256 + threadIdx.x;   // 2^21 threads exact
  int i = idx & 15, h = (idx >> 4) & 15, s = (idx >> 8) & 2047, b = idx >> 19;
  long base = (long)(b * 2048 + s) * 1536 + 1024 + h * 32 + 2 * i;
  float x1 = b2f(C2[base]), x2 = b2f(C2[base + 1]);
  float inv = exp2f(-(float)i * 0.8304820237686285f);  // 10000^(-i/16)
  float ang = (float)s * inv;
  float c = cosf(ang), sn = sinf(ang);
  C2[base]     = f2b(x1 * c - x2 * sn);
  C2[base + 1] = f2b(x1 * sn + x2 * c);
}

// ---------------- RoPE on Kr: C1 cols 512+2i -> Krr (B*S x 32) ----------------
__global__ __launch_bounds__(256) void rope_k(const unsigned short* __restrict__ C1,
                                              unsigned short* __restrict__ Krr) {
  int idx = blockIdx.x * 256 + threadIdx.x;   // 2^17 threads exact
  int i = idx & 15, s = (idx >> 4) & 2047, b = idx >> 15;
  long src = (long)(b * 2048 + s) * 544 + 512 + 2 * i;
  float x1 = b2f(C1[src]), x2 = b2f(C1[src + 1]);
  float inv = exp2f(-(float)i * 0.8304820237686285f);
  float ang = (float)s * inv;
  float c = cosf(ang), sn = sinf(ang);
  long dst = (long)(b * 2048 + s) * 32 + 2 * i;
  Krr[dst]     = f2b(x1 * c - x2 * sn);
  Krr[dst + 1] = f2b(x1 * sn + x2 * c);
}

// ---------------- GEMM: C(M x N) = A(M x K, lda) @ Bt(N x K, ldb)^T ----------------
template <bool OUT_BF16>
__global__ __launch_bounds__(256) void gemm_bt(const unsigned short* __restrict__ A, int lda,
                                               const unsigned short* __restrict__ Bt, int ldb,
                                               void* __restrict__ Cv, int ldc, int N, int K) {
  __shared__ __align__(16) unsigned short As[128 * 32];
  __shared__ __align__(16) unsigned short Bs[128 * 32];
  const int t = threadIdx.x;
  const int w = t >> 6, lane = t & 63, ln = lane & 15, quad = lane >> 4;
  const int wr = w >> 1, wc = w & 1;
  const int bm0 = blockIdx.x * 128, bn0 = blockIdx.y * 128;
  const int srow = t >> 2;          // 0..63
  const int scol = (t & 3) * 8;     // 0,8,16,24
  f32x4 zero = {0.f, 0.f, 0.f, 0.f};
  f32x4 acc[4][4];
#pragma unroll
  for (int i = 0; i < 4; ++i)
#pragma unroll
    for (int j = 0; j < 4; ++j) acc[i][j] = zero;

  for (int k0 = 0; k0 < K; k0 += 32) {
#pragma unroll
    for (int r = 0; r < 2; ++r) {
      int arow = bm0 + r * 64 + srow;
      load_lds16(A + (long)arow * lda + k0 + scol, (char*)As + r * 4096 + w * 1024);
      int brow = bn0 + r * 64 + srow;
      if (brow > N - 1) brow = N - 1;  // clamp (garbage cols guarded at write)
      load_lds16(Bt + (long)brow * ldb + k0 + scol, (char*)Bs + r * 4096 + w * 1024);
    }
    __syncthreads();
    bf16x8 af[4], bf[4];
#pragma unroll
    for (int i = 0; i < 4; ++i)
      af[i] = *(const bf16x8*)(As + (wr * 64 + i * 16 + ln) * 32 + quad * 8);
#pragma unroll
    for (int j = 0; j < 4; ++j)
      bf[j] = *(const bf16x8*)(Bs + (wc * 64 + j * 16 + ln) * 32 + quad * 8);
#pragma unroll
    for (int i = 0; i < 4; ++i)
#pragma unroll
      for (int j = 0; j < 4; ++j) acc[i][j] = mfma16(af[i], bf[j], acc[i][j]);
    __syncthreads();
  }
#pragma unroll
  for (int i = 0; i < 4; ++i)
#pragma unroll
    for (int j = 0; j < 4; ++j)
#pragma unroll
      for (int r = 0; r < 4; ++r) {
        int row = bm0 + wr * 64 + i * 16 + quad * 4 + r;
        int col = bn0 + wc * 64 + j * 16 + ln;
        if (col < N) {
          if (OUT_BF16)
            ((unsigned short*)Cv)[(long)row * ldc + col] = f2b(acc[i][j][r]);
          else
            ((float*)Cv)[(long)row * ldc + col] = acc[i][j][r];
        }
      }
}

// ---------------- Flash attention v2 ----------------
// grid (16, 64): blockIdx.x -> qi = 15-x (LPT: heavy blocks first), blockIdx.y = bh.
// Block: 128 Q rows (wave w owns 32). 64-key tiles double-buffered in LDS,
// cooperatively staged via global_load_lds with XOR chunk swizzle.
// Softmax uses fixed max M = 80/sqrt(96) (scores are clipped to +-80 pre-scale,
// so exp(z-M) is always in [e^-16.3, 1]) -> no running max, no rescale, no shuffles.
// Row-sum l computed by mfma(P, ones).
__global__ __launch_bounds__(256, 2) void flash_attn(const unsigned short* __restrict__ C2,
                                                     const unsigned short* __restrict__ C3,
                                                     const unsigned short* __restrict__ Krr,
                                                     const unsigned short* __restrict__ Vt,
                                                     unsigned short* __restrict__ Oa) {
  __shared__ __align__(16) unsigned short Ks[2][4096];   // 64 keys x 64 dims (swizzled 16B chunks)
  __shared__ __align__(16) unsigned short Krs[2][2048];  // 64 keys x 32 dims
  __shared__ __align__(16) unsigned short Vs[2][4096];   // 64 d    x 64 keys
  __shared__ __align__(16) unsigned short Ps[4][1024];   // per-wave P: 16 q x 64 keys

  const int tid = threadIdx.x;
  const int w = tid >> 6, lane = tid & 63, ln = lane & 15, quad = lane >> 4;
  const int bh = blockIdx.y, b = bh >> 4, h = bh & 15;
  const int bS = b * 2048;
  const int qi = 15 - blockIdx.x;          // LPT order
  const int qb = qi * 128 + w * 32;
  const int nkt = 2 * qi + 2;
  const float KSC  = 0.10206207261596577f;  // 1/sqrt(96)
  const float KOFF = 8.16496580927726f;     // 80/sqrt(96): hard bound on clipped*scaled score
  const bf16x8 kones = ones8();

  // Q fragments (from C2: Qc at h*64, roped Qr at 1024+h*32)
  bf16x8 qf[2][3];
#pragma unroll
  for (int mi = 0; mi < 2; ++mi) {
    const unsigned short* qp = C2 + (long)(bS + qb + mi * 16 + ln) * 1536;
    qf[mi][0] = *(const bf16x8*)(qp + h * 64 + quad * 8);
    qf[mi][1] = *(const bf16x8*)(qp + h * 64 + 32 + quad * 8);
    qf[mi][2] = *(const bf16x8*)(qp + 1024 + h * 32 + quad * 8);
  }

  f32x4 zero = {0.f, 0.f, 0.f, 0.f};
  f32x4 o[2][4], lacc[2];
#pragma unroll
  for (int mi = 0; mi < 2; ++mi) {
    lacc[mi] = zero;
#pragma unroll
    for (int nb = 0; nb < 4; ++nb) o[mi][nb] = zero;
  }

  // Cooperative staging of one 64-key tile into buffer `buf`.
  // Swizzle: 16B chunk c of row r stored at slot (c ^ sw(r)); applied by
  // permuting the SOURCE address (dst of global_load_lds must be lane-contiguous).
  auto stage = [&](int buf, int key0) {
#pragma unroll
    for (int t = w; t < 8; t += 4) {   // Kc: 64 rows x 128B
      int ci = t * 64 + lane;
      int r = ci >> 3, c = (ci & 7) ^ (r & 7);
      load_lds16(C3 + (size_t)(bS + key0 + r) * 2048 + h * 64 + c * 8, &Ks[buf][t * 512]);
    }
    {                                   // Kr: 64 rows x 64B
      int ci = w * 64 + lane;
      int r = ci >> 2, c = (ci & 3) ^ ((r & 3) ^ ((r >> 2) & 3));
      load_lds16(Krr + (size_t)(bS + key0 + r) * 32 + c * 8, &Krs[buf][w * 512]);
    }
#pragma unroll
    for (int t = w; t < 8; t += 4) {   // V^T: 64 d-rows x 128B
      int ci = t * 64 + lane;
      int r = ci >> 3, c = (ci & 7) ^ (r & 7);
      load_lds16(Vt + (size_t)((size_t)bh * 64 + r) * 2048 + key0 + c * 8, &Vs[buf][t * 512]);
    }
  };

  stage(0, 0);
  for (int kt = 0; kt < nkt; ++kt) {
    __syncthreads();                    // drains vmcnt(0): stage(kt) visible to all
    if (kt + 1 < nkt) stage((kt + 1) & 1, (kt + 1) * 64);
    const int c0 = kt * 64;
    if (c0 > qb + 31) continue;         // fully-masked tile for this wave: barriers only

    const unsigned short* Kp  = Ks[kt & 1];
    const unsigned short* Krp = Krs[kt & 1];
    const unsigned short* Vp  = Vs[kt & 1];

    f32x4 s0[4], s1[4];
#pragma unroll
    for (int ni = 0; ni < 4; ++ni) { s0[ni] = zero; s1[ni] = zero; }
#pragma unroll
    for (int ni = 0; ni < 4; ++ni) {
      int key = ni * 16 + ln;
      bf16x8 kf0 = *(const bf16x8*)(Kp + key * 64 + ((quad ^ (key & 7)) * 8));
      bf16x8 kf1 = *(const bf16x8*)(Kp + key * 64 + (((4 | quad) ^ (key & 7)) * 8));
      bf16x8 kf2 = *(const bf16x8*)(Krp + key * 32 + ((quad ^ ((key & 3) ^ ((key >> 2) & 3))) * 8));
      s0[ni] = mfma16(qf[0][0], kf0, s0[ni]);
      s0[ni] = mfma16(qf[0][1], kf1, s0[ni]);
      s0[ni] = mfma16(qf[0][2], kf2, s0[ni]);
      s1[ni] = mfma16(qf[1][0], kf0, s1[ni]);
      s1[ni] = mfma16(qf[1][1], kf1, s1[ni]);
      s1[ni] = mfma16(qf[1][2], kf2, s1[ni]);
    }
    bf16x8 vf[4][2];
#pragma unroll
    for (int nb = 0; nb < 4; ++nb) {
      int d = nb * 16 + ln;
#pragma unroll
      for (int ks = 0; ks < 2; ++ks)
        vf[nb][ks] = *(const bf16x8*)(Vp + d * 64 + (((ks * 4 + quad) ^ (d & 7)) * 8));
    }

#pragma unroll
    for (int mi = 0; mi < 2; ++mi) {
      f32x4* sp = mi ? s1 : s0;
      const bool nm = (c0 + 63) > (qb + mi * 16);  // tile touches the diagonal
      unsigned short* P = Ps[w];
#pragma unroll
      for (int ni = 0; ni < 4; ++ni)
#pragma unroll
        for (int r = 0; r < 4; ++r) {
          float t = fminf(fmaxf(sp[ni][r], -80.f), 80.f);    // clip BEFORE scale (ref order)
          float z = fmaf(t, KSC, -KOFF);                     // z - M, z <= M guaranteed
          if (nm && (c0 + ni * 16 + ln) > (qb + mi * 16 + quad * 4 + r)) z = -1e30f;
          int q = quad * 4 + r;
          P[q * 64 + (((ni * 2 + (ln >> 3)) ^ (q & 7)) * 8) + (ln & 7)] = f2b(__expf(z));
        }
      __threadfence_block();   // drain P writes before A-layout reads (same wave)
      bf16x8 pf0 = *(const bf16x8*)(P + ln * 64 + ((quad ^ (ln & 7)) * 8));
      bf16x8 pf1 = *(const bf16x8*)(P + ln * 64 + (((4 | quad) ^ (ln & 7)) * 8));
      lacc[mi] = mfma16(pf0, kones, lacc[mi]);   // row-sum of P via MFMA
      lacc[mi] = mfma16(pf1, kones, lacc[mi]);
#pragma unroll
      for (int nb = 0; nb < 4; ++nb) {
        o[mi][nb] = mfma16(pf0, vf[nb][0], o[mi][nb]);
        o[mi][nb] = mfma16(pf1, vf[nb][1], o[mi][nb]);
      }
      __threadfence_block();   // P reads retired before next mi overwrites
    }
  }

  // epilogue: Oa layout (B,S,H*64) bf16; lacc same C-layout as o
#pragma unroll
  for (int mi = 0; mi < 2; ++mi) {
    float rl[4];
#pragma unroll
    for (int r = 0; r < 4; ++r) rl[r] = 1.0f / lacc[mi][r];
#pragma unroll
    for (int nb = 0; nb < 4; ++nb)
#pragma unroll
      for (int r = 0; r < 4; ++r) {
        long row = (long)(bS + qb + mi * 16 + quad * 4 + r);
        Oa[row * 1024 + h * 64 + nb * 16 + ln] = f2b(o[mi][nb][r] * rl[r]);
      }
  }
}

// ---------------- launcher ----------------
extern "C" void kernel_launch(void* const* d_in, const int* in_sizes, int n_in,
                              void* d_out, int out_size, void* d_ws, size_t ws_size,
                              hipStream_t stream) {
  (void)in_sizes; (void)n_in; (void)out_size; (void)ws_size;
  const float* x     = (const float*)d_in[0];
  const float* W_DQ  = (const float*)d_in[1];
  const float* W_UQ  = (const float*)d_in[2];
  const float* W_QR  = (const float*)d_in[3];
  const float* W_DKV = (const float*)d_in[4];
  const float* W_UK  = (const float*)d_in[5];
  const float* W_UV  = (const float*)d_in[6];
  const float* W_KR  = (const float*)d_in[7];
  const float* W_O   = (const float*)d_in[8];

  char* p = (char*)d_ws;
  unsigned short* xb  = (unsigned short*)p; p += (size_t)8192 * 1024 * 2;
  unsigned short* WT1 = (unsigned short*)p; p += (size_t)544 * 1024 * 2;   // [W_DQ^T; W_DKV^T; W_KR^T]
  unsigned short* WT2 = (unsigned short*)p; p += (size_t)1536 * 256 * 2;   // [W_UQ^T; W_QR^T]
  unsigned short* WT3 = (unsigned short*)p; p += (size_t)2048 * 256 * 2;   // [W_UK^T; W_UV^T]
  unsigned short* WT4 = (unsigned short*)p; p += (size_t)1024 * 1024 * 2;  // W_O^T
  unsigned short* C1  = (unsigned short*)p; p += (size_t)8192 * 544 * 2;   // [c_q | c_kv | kr_raw]
  unsigned short* C2  = (unsigned short*)p; p += (size_t)8192 * 1536 * 2;  // [Qc | Qr(roped in-place)]
  unsigned short* C3  = (unsigned short*)p; p += (size_t)8192 * 2048 * 2;  // [Kc | V]
  unsigned short* Krr = (unsigned short*)p; p += (size_t)8192 * 32 * 2;    // roped Kr
  unsigned short* Vt  = (unsigned short*)p; p += (size_t)64 * 64 * 2048 * 2;
  unsigned short* Oa  = (unsigned short*)p; p += (size_t)8192 * 1024 * 2;  // attn out (B,S,1024)

  convert_x<<<8192, 256, 0, stream>>>(x, xb);
  transpose_w<<<dim3(8, 32),  256, 0, stream>>>(W_DQ,  WT1,              1024, 256);
  transpose_w<<<dim3(8, 32),  256, 0, stream>>>(W_DKV, WT1 + 256 * 1024, 1024, 256);
  transpose_w<<<dim3(1, 32),  256, 0, stream>>>(W_KR,  WT1 + 512 * 1024, 1024, 32);
  transpose_w<<<dim3(32, 8),  256, 0, stream>>>(W_UQ,  WT2,              256, 1024);
  transpose_w<<<dim3(16, 8),  256, 0, stream>>>(W_QR,  WT2 + 1024 * 256, 256, 512);
  transpose_w<<<dim3(32, 8),  256, 0, stream>>>(W_UK,  WT3,              256, 1024);
  transpose_w<<<dim3(32, 8),  256, 0, stream>>>(W_UV,  WT3 + 1024 * 256, 256, 1024);
  transpose_w<<<dim3(32, 32), 256, 0, stream>>>(W_O,   WT4,              1024, 1024);

  gemm_bt<true><<<dim3(64, 5),  256, 0, stream>>>(xb, 1024, WT1, 1024, C1, 544, 544, 1024);
  rope_k<<<512, 256, 0, stream>>>(C1, Krr);
  gemm_bt<true><<<dim3(64, 12), 256, 0, stream>>>(C1, 544, WT2, 256, C2, 1536, 1536, 256);
  gemm_bt<true><<<dim3(64, 16), 256, 0, stream>>>(C1 + 256, 544, WT3, 256, C3, 2048, 2048, 256);
  rope_q<<<8192, 256, 0, stream>>>(C2);
  transpose_v<<<dim3(2, 64, 64), 256, 0, stream>>>(C3, Vt);
  flash_attn<<<dim3(16, 64), 256, 0, stream>>>(C2, C3, Krr, Vt, Oa);
  gemm_bt<false><<<dim3(64, 8), 256, 0, stream>>>(Oa, 1024, WT4, 1024, d_out, 1024, 1024, 1024);
}